// Round 1
// baseline (113.557 us; speedup 1.0000x reference)
//
#include <hip/hip_runtime.h>
#include <hip/hip_bf16.h>

// HybridSurvivalQ: quantum expval collapses to prod_{q=1..6} cos(x_q[q]+p[q])
// (CNOT ring permutes basis states; final bit0 = parity of bits 1..6;
//  E[(-1)^{b_q}] = cos^2-sin^2 = cos(x+p) per qubit; qubit 0 marginalizes out).
// Then MLP 65->32->16->1 with ReLU. One thread per row, fp32 vector ALU.
//
// R1 lesson: dur_us (~113us) is dominated by harness reset fills (268MB d_ws
//   poisons, 42-45us each); our kernel is <42us and invisible in top-5.
// R2 lesson: rolled layer-2 loop indexed acc1[k] with runtime k -> array
//   spilled to scratch; scratch + graph-replay produced post-timing-only
//   divergence. NO runtime-indexed per-thread arrays allowed.
// R3 change (this round): at 2 waves/SIMD (2048 waves total, grid-limited)
//   TLP cannot hide load latency, and the rolled layer-1 loop kept exactly
//   ONE float4 load in flight per iteration (serial load->wait->128FMA).
//   Now: issue all 22 per-row loads up front (6 xq + 16 float4 xc, 64 VGPR),
//   fully unroll layer 1 so all xv[]/acc1[] indices are compile-time
//   constant (no scratch per R2). One ~900cy latency exposure instead of 16;
//   compiler drains vmcnt progressively under the FMA stream.

#define NQ 7
#define F  64
#define H1 32
#define H2 16

__global__ __launch_bounds__(256) void hybrid_fused(
    const float* __restrict__ x_q, const float* __restrict__ x_c,
    const float* __restrict__ q_params,
    const float* __restrict__ W1, const float* __restrict__ b1,
    const float* __restrict__ W2, const float* __restrict__ b2,
    const float* __restrict__ W3, const float* __restrict__ b3,
    float* __restrict__ out, int B)
{
    const int row = blockIdx.x * 256 + threadIdx.x;
    if (row >= B) return;

    // ---- issue ALL per-row global loads up front (22 independent loads) ----
    float xq[NQ - 1];
    #pragma unroll
    for (int q = 1; q < NQ; ++q)
        xq[q - 1] = x_q[(size_t)row * NQ + q];

    const float4* xc4 = reinterpret_cast<const float4*>(x_c + (size_t)row * F);
    float4 xv[F / 4];
    #pragma unroll
    for (int i = 0; i < F / 4; ++i)
        xv[i] = xc4[i];

    // ---- quantum expectation (closed form); waits only on the 6 xq loads,
    //      the 16 xc loads stay in flight underneath ----
    float qv = 1.0f;
    #pragma unroll
    for (int q = 1; q < NQ; ++q)
        qv *= __cosf(xq[q - 1] + q_params[q]);

    // ---- layer 1: combined(65) @ W1(65x32) + b1 ----
    // combined[0] = qv, combined[1+f] = x_c[f]
    float acc1[H1];
    #pragma unroll
    for (int j = 0; j < H1; ++j)
        acc1[j] = fmaf(qv, W1[j], b1[j]);   // k = 0 row of W1 (constant idx)

    // FULLY unrolled: xv[k4] constant-indexed -> registers; weights are
    // wave-uniform s_load_dwordx16 batches at constant imm offsets.
    #pragma unroll
    for (int k4 = 0; k4 < F / 4; ++k4) {
        const float* w = W1 + (size_t)(1 + 4 * k4) * H1;
        #pragma unroll
        for (int j = 0; j < H1; ++j) acc1[j] = fmaf(xv[k4].x, w[j],          acc1[j]);
        #pragma unroll
        for (int j = 0; j < H1; ++j) acc1[j] = fmaf(xv[k4].y, w[H1 + j],     acc1[j]);
        #pragma unroll
        for (int j = 0; j < H1; ++j) acc1[j] = fmaf(xv[k4].z, w[2 * H1 + j], acc1[j]);
        #pragma unroll
        for (int j = 0; j < H1; ++j) acc1[j] = fmaf(xv[k4].w, w[3 * H1 + j], acc1[j]);
    }

    // ---- layer 2: relu(acc1)(32) @ W2(32x16) + b2 ----
    // FULLY unrolled: all acc1/acc2 indices constant -> registers, no scratch.
    float acc2[H2];
    #pragma unroll
    for (int j = 0; j < H2; ++j) acc2[j] = b2[j];
    #pragma unroll
    for (int k = 0; k < H1; ++k) {
        const float h = fmaxf(acc1[k], 0.0f);
        #pragma unroll
        for (int j = 0; j < H2; ++j)
            acc2[j] = fmaf(h, W2[k * H2 + j], acc2[j]);
    }

    // ---- layer 3: relu(acc2)(16) @ W3(16x1) + b3 ----
    float o = b3[0];
    #pragma unroll
    for (int k = 0; k < H2; ++k)
        o = fmaf(fmaxf(acc2[k], 0.0f), W3[k], o);

    out[row] = o;
}

extern "C" void kernel_launch(void* const* d_in, const int* in_sizes, int n_in,
                              void* d_out, int out_size, void* d_ws, size_t ws_size,
                              hipStream_t stream) {
    const float* x_q      = (const float*)d_in[0];
    const float* x_c      = (const float*)d_in[1];
    const float* q_params = (const float*)d_in[2];
    const float* W1       = (const float*)d_in[3];
    const float* b1       = (const float*)d_in[4];
    const float* W2       = (const float*)d_in[5];
    const float* b2       = (const float*)d_in[6];
    const float* W3       = (const float*)d_in[7];
    const float* b3       = (const float*)d_in[8];
    float* out = (float*)d_out;

    const int B = in_sizes[0] / NQ;   // 131072
    const int grid = (B + 255) / 256; // 512 blocks of 256

    hybrid_fused<<<grid, 256, 0, stream>>>(x_q, x_c, q_params,
                                           W1, b1, W2, b2, W3, b3,
                                           out, B);
}

// Round 2
// 105.078 us; speedup vs baseline: 1.0807x; 1.0807x over previous
//
#include <hip/hip_runtime.h>
#include <hip/hip_bf16.h>

// HybridSurvivalQ: quantum expval collapses to prod_{q=1..6} cos(x_q[q]+p[q])
// (CNOT ring permutes basis states; final bit0 = parity of bits 1..6;
//  E[(-1)^{b_q}] = cos^2-sin^2 = cos(x+p) per qubit; qubit 0 marginalizes out).
// Then MLP 65->32->16->1 with ReLU. One thread per row, fp32 vector ALU.
//
// R1 lesson: dur_us is dominated by harness reset fills (268MB d_ws poisons,
//   42-45us each, 2-3 per timed iteration); our kernel is <42us, not in top-5.
// R2 lesson: runtime-indexed per-thread arrays -> scratch spill + post-timing
//   divergence under graph replay. All acc/xv indices must be compile-time.
// R3 lesson (REGRESSION, 102.2 -> 113.6us): full unroll of layer-1 with all
//   16 float4 loads issued up front made it WORSE than the rolled loop —
//   64 pinned VGPRs + 21KB straight-line body + serialized SGPR weight
//   batches beat the compiler's own pipelining of the compact loop. Reverted.
// R4 change: keep the PROVEN rolled structure (102.2us) and fix its one real
//   flaw minimally: manual 1-deep pipeline. Load next iteration's float4
//   before the 128-FMA body, so each load has a full iteration (~300cy of
//   FMA) to complete -> per-iteration latency exposure eliminated, code
//   stays a ~1KB hot loop, +4 VGPRs only.

#define NQ 7
#define F  64
#define H1 32
#define H2 16

// 128-FMA layer-1 sub-block: acc1 += outer(xv, W1[rows 1+4k..4+4k])
#define L1_BODY(XV, WPTR)                                                    \
    do {                                                                     \
        const float* w_ = (WPTR);                                            \
        _Pragma("unroll")                                                    \
        for (int j = 0; j < H1; ++j) acc1[j] = fmaf((XV).x, w_[j],          acc1[j]); \
        _Pragma("unroll")                                                    \
        for (int j = 0; j < H1; ++j) acc1[j] = fmaf((XV).y, w_[H1 + j],     acc1[j]); \
        _Pragma("unroll")                                                    \
        for (int j = 0; j < H1; ++j) acc1[j] = fmaf((XV).z, w_[2 * H1 + j], acc1[j]); \
        _Pragma("unroll")                                                    \
        for (int j = 0; j < H1; ++j) acc1[j] = fmaf((XV).w, w_[3 * H1 + j], acc1[j]); \
    } while (0)

__global__ __launch_bounds__(256) void hybrid_fused(
    const float* __restrict__ x_q, const float* __restrict__ x_c,
    const float* __restrict__ q_params,
    const float* __restrict__ W1, const float* __restrict__ b1,
    const float* __restrict__ W2, const float* __restrict__ b2,
    const float* __restrict__ W3, const float* __restrict__ b3,
    float* __restrict__ out, int B)
{
    const int row = blockIdx.x * 256 + threadIdx.x;
    if (row >= B) return;

    // ---- quantum expectation (closed form) ----
    float qv = 1.0f;
    #pragma unroll
    for (int q = 1; q < NQ; ++q) {
        qv *= __cosf(x_q[(size_t)row * NQ + q] + q_params[q]);
    }

    // ---- layer 1: combined(65) @ W1(65x32) + b1 ----
    // combined[0] = qv, combined[1+f] = x_c[f]
    float acc1[H1];
    #pragma unroll
    for (int j = 0; j < H1; ++j)
        acc1[j] = fmaf(qv, W1[j], b1[j]);   // k = 0 row of W1 (constant idx)

    const float4* xc4 = reinterpret_cast<const float4*>(x_c + (size_t)row * F);

    // Rolled loop (proven structure) + 1-deep manual pipeline: nxt load is
    // issued before the FMA body, consumed next iteration -> its waitcnt
    // lands a full 128-FMA body after issue.
    float4 cur = xc4[0];
    #pragma unroll 1
    for (int k4 = 0; k4 < F / 4 - 1; ++k4) {
        const float4 nxt = xc4[k4 + 1];
        L1_BODY(cur, W1 + (size_t)(1 + 4 * k4) * H1);
        cur = nxt;
    }
    // epilogue: last sub-block, no further load
    L1_BODY(cur, W1 + (size_t)(1 + 4 * (F / 4 - 1)) * H1);

    // ---- layer 2: relu(acc1)(32) @ W2(32x16) + b2 ----
    // FULLY unrolled: all acc1/acc2 indices constant -> registers, no scratch.
    float acc2[H2];
    #pragma unroll
    for (int j = 0; j < H2; ++j) acc2[j] = b2[j];
    #pragma unroll
    for (int k = 0; k < H1; ++k) {
        const float h = fmaxf(acc1[k], 0.0f);
        #pragma unroll
        for (int j = 0; j < H2; ++j)
            acc2[j] = fmaf(h, W2[k * H2 + j], acc2[j]);
    }

    // ---- layer 3: relu(acc2)(16) @ W3(16x1) + b3 ----
    float o = b3[0];
    #pragma unroll
    for (int k = 0; k < H2; ++k)
        o = fmaf(fmaxf(acc2[k], 0.0f), W3[k], o);

    out[row] = o;
}

extern "C" void kernel_launch(void* const* d_in, const int* in_sizes, int n_in,
                              void* d_out, int out_size, void* d_ws, size_t ws_size,
                              hipStream_t stream) {
    const float* x_q      = (const float*)d_in[0];
    const float* x_c      = (const float*)d_in[1];
    const float* q_params = (const float*)d_in[2];
    const float* W1       = (const float*)d_in[3];
    const float* b1       = (const float*)d_in[4];
    const float* W2       = (const float*)d_in[5];
    const float* b2       = (const float*)d_in[6];
    const float* W3       = (const float*)d_in[7];
    const float* b3       = (const float*)d_in[8];
    float* out = (float*)d_out;

    const int B = in_sizes[0] / NQ;   // 131072
    const int grid = (B + 255) / 256; // 512 blocks of 256

    hybrid_fused<<<grid, 256, 0, stream>>>(x_q, x_c, q_params,
                                           W1, b1, W2, b2, W3, b3,
                                           out, B);
}